// Round 16
// baseline (321.305 us; speedup 1.0000x reference)
//
#include <hip/hip_runtime.h>

typedef __bf16 bf16_t;
typedef __bf16 bf16x8 __attribute__((ext_vector_type(8)));
typedef __bf16 bf16x4 __attribute__((ext_vector_type(4)));
typedef float f32x4 __attribute__((ext_vector_type(4)));
typedef float f32x16 __attribute__((ext_vector_type(16)));
typedef short s16x4 __attribute__((ext_vector_type(4)));
typedef short s16x8 __attribute__((ext_vector_type(8)));
typedef unsigned u32x2 __attribute__((ext_vector_type(2)));

#define MFMA16(A_, B_, C_) __builtin_amdgcn_mfma_f32_16x16x32_bf16((A_), (B_), (C_), 0, 0, 0)
#define MFMA32(A_, B_, C_) __builtin_amdgcn_mfma_f32_32x32x16_bf16((A_), (B_), (C_), 0, 0, 0)

// softmax scale folded into Q at GEMM0: 0.125 * log2(e) so p = exp2(s - m)
#define QSC 0.18033688011112042f

#if __has_builtin(__builtin_amdgcn_exp2f)
#define EXP2F(x) __builtin_amdgcn_exp2f(x)
#else
#define EXP2F(x) exp2f(x)
#endif

__device__ __forceinline__ void gload_lds16(const bf16_t* g, bf16_t* l) {
  __builtin_amdgcn_global_load_lds(
      (const __attribute__((address_space(1))) void*)g,
      (__attribute__((address_space(3))) void*)l, 16, 0, 0);
}

__device__ __forceinline__ unsigned cvt_pk_bf16(float a, float b) {
  unsigned r;
  asm("v_cvt_pk_bf16_f32 %0, %1, %2" : "=v"(r) : "v"(a), "v"(b));
  return r;
}

// HW transpose read (attn). Lane l supplies chunk_base + (l&15)*8B and
// receives column (l&15): elem j = chunk[j][l&15] of a 4x16-bf16 tile.
__device__ __forceinline__ s16x4 tr_b16(const bf16_t* p) {
  s16x4 d;
  unsigned off = (unsigned)(size_t)(const __attribute__((address_space(3))) bf16_t*)p;
  asm volatile("ds_read_b64_tr_b16 %0, %1" : "=v"(d) : "v"(off));
  return d;
}

// b128 LDS read as volatile inline asm: no compiler-inserted waits; ordering
// is the explicit vmcnt/lgkmcnt/barrier discipline documented per kernel.
union B128 { s16x8 s; bf16x8 b; };

#define DSR(PTR, U)                                                           \
  do {                                                                        \
    unsigned _o = (unsigned)(size_t)                                          \
        (const __attribute__((address_space(3))) bf16_t*)(PTR);               \
    asm volatile("ds_read_b128 %0, %1" : "=v"((U).s) : "v"(_o));              \
  } while (0)

// b128 read from hoisted base register + 16-bit immediate offset.
#define DSR_OFS(BASEV, OFFSTR, U)                                             \
  asm volatile("ds_read_b128 %0, %1 offset:" OFFSTR                           \
               : "=v"((U).s) : "v"(BASEV))

// v_permlane32_swap_b32(vdst=b, vsrc=a): rb={b.lo,a.lo}, ra={b.hi,a.hi}.
__device__ __forceinline__ void swap32(unsigned a, unsigned b, int hi,
                                       unsigned& ra, unsigned& rb) {
#if __has_builtin(__builtin_amdgcn_permlane32_swap)
  u32x2 r = __builtin_amdgcn_permlane32_swap(b, a, false, false);
  rb = r[0]; ra = r[1];
#else
  unsigned bx = (unsigned)__shfl_xor((int)b, 32);
  unsigned ax = (unsigned)__shfl_xor((int)a, 32);
  ra = hi ? a : bx;
  rb = hi ? ax : b;
#endif
}

// fp32 -> bf16, 4 elements/thread
__global__ __launch_bounds__(256) void k_convert(const float* __restrict__ in,
                                                 bf16_t* __restrict__ out, int n4) {
  int i = blockIdx.x * 256 + threadIdx.x;
  if (i >= n4) return;
  float4 v = ((const float4*)in)[i];
  bf16x4 o;
  o[0] = (__bf16)v.x; o[1] = (__bf16)v.y; o[2] = (__bf16)v.z; o[3] = (__bf16)v.w;
  *(bf16x4*)(out + (size_t)i * 4) = o;
}

// out[c][r] = (bf16) in[r][c];  in is [R][C] fp32. 64x64 tiles, 256 threads.
__global__ __launch_bounds__(256) void k_transpose(const float* __restrict__ in,
                                                   bf16_t* __restrict__ out, int R, int C) {
  __shared__ float tile[64][65];
  int tx = threadIdx.x & 63;
  int ty = threadIdx.x >> 6;
  int bc = blockIdx.x * 64;
  int br = blockIdx.y * 64;
#pragma unroll
  for (int i = ty; i < 64; i += 4)
    tile[i][tx] = in[(size_t)(br + i) * C + bc + tx];
  __syncthreads();
#pragma unroll
  for (int i = ty; i < 64; i += 4)
    out[(size_t)(bc + i) * R + br + tx] = (bf16_t)tile[tx][i];
}

// block-split row permutation: original token row -> attention-layout row
__device__ __forceinline__ int permrow(int r) {
  int b  = r >> 12;
  int l  = r & 4095;
  int ix = (l >> 11) & 1;
  int sx = (l >> 6) & 31;
  int iy = (l >> 5) & 1;
  int sy = l & 31;
  return (b << 12) + (ix << 11) + (iy << 10) + (sx << 5) + sy;
}

#define SBAR __builtin_amdgcn_sched_barrier(0)

// ---------------------------------------------------------------------------
// k_gemm15<MODE> round-16: r15 structure + COUNTED-lgkmcnt intra-wave
// pipelining. Profile model: per CU per K-tile the 128 ds_read_b128 (128 KB)
// = ~1540 cyc LDS-BW floor; MFMA wall = ~310 cyc. The old lgkm0-then-MFMA
// serialized a full MFMA+sync tail after the DS drain (measured 3024).
// Now reads are ordered [8xB, af0, af1, af2, af3] and MFMA m-steps start as
// operands land: lgkmcnt(6)->m0, (4)->m1, (2)->m2, (0)->m3 (DS ops retire
// in order; gload_lds is vmcnt-only so counts are pure-DS). sched_barrier
// after each wait (rule 18). Stage/vmcnt ledger identical to r15.
// MODE 0: fused QKV (TN=24, grid 768 = 3 clean block-waves), permuted bf16.
// MODE 1: output proj (TN=16, grid 512 = 2 clean waves), fp32 out.
// ---------------------------------------------------------------------------
#define LA(K_) (lds + (K_)*24576)
#define LB(K_) (lds + (K_)*24576 + 16384)

template <int MODE>
__global__ __launch_bounds__(512, 2) void k_gemm15(
    const bf16_t* __restrict__ A,
    const bf16_t* __restrict__ B0, const bf16_t* __restrict__ B1,
    const bf16_t* __restrict__ B2,
    bf16_t* __restrict__ Cq, bf16_t* __restrict__ Ck, bf16_t* __restrict__ Cv,
    float* __restrict__ Cf) {
  extern __shared__ bf16_t lds[];

  const int TN = (MODE == 0) ? 24 : 16;
  int bid = blockIdx.x;
  int s = bid >> 3;
  int tm = (bid & 7) * 4 + s / TN;  // 0..31 (256-row tiles)
  int tn = s % TN;                  // 128-col tiles

  const bf16_t* Bp;
  int brow;
  if (MODE == 0) {
    if (tn < 16)      { Bp = B0; brow = tn << 7; }
    else if (tn < 20) { Bp = B1; brow = (tn - 16) << 7; }
    else              { Bp = B2; brow = (tn - 20) << 7; }
  } else {
    Bp = B0; brow = tn << 7;
  }

  int tid = threadIdx.x;
  int lane = tid & 63;
  int w = tid >> 6;                  // 0..7
  int wm = w >> 1, wn = w & 1;       // 4M x 2N wave grid
  int g16 = lane >> 4, cl = lane & 15;
  int swz8 = (cl & 7) << 3;
  int wofs = w << 9;

  int srow = tid >> 3;                                  // 0..63
  int lc = (((tid & 7) ^ (srow & 7)) << 3);             // pre-swizzled col
  const bf16_t* aBt = A + (size_t)(tm * 256 + srow) * 2048 + lc;
  const bf16_t* bBt = Bp + (size_t)(brow + srow) * 2048 + lc;

  // 12 loop-invariant per-lane LDS base byte-addresses
  unsigned ldsb = (unsigned)(size_t)(__attribute__((address_space(3))) bf16_t*)lds;
  unsigned arow0 = (unsigned)((wm * 64 + cl) * 128 + (((g16 * 8) ^ swz8) << 1));
  unsigned arow1 = (unsigned)((wm * 64 + cl) * 128 + ((((32 + g16 * 8)) ^ swz8) << 1));
  unsigned brow0 = (unsigned)(32768 + (wn * 64 + cl) * 128 + (((g16 * 8) ^ swz8) << 1));
  unsigned brow1 = (unsigned)(32768 + (wn * 64 + cl) * 128 + ((((32 + g16 * 8)) ^ swz8) << 1));
  unsigned a0[3], a1[3], b0[3], b1[3];
#pragma unroll
  for (int kk = 0; kk < 3; ++kk) {
    a0[kk] = ldsb + kk * 49152 + arow0;
    a1[kk] = ldsb + kk * 49152 + arow1;
    b0[kk] = ldsb + kk * 49152 + brow0;
    b1[kk] = ldsb + kk * 49152 + brow1;
  }

#define GA_STAGE(K2_)                                                          \
  _Pragma("unroll") for (int rr = 0; rr < 4; ++rr)                             \
    gload_lds16(aBt + (size_t)(rr * 64) * 2048, LA(K2_) + rr * 4096 + wofs);   \
  _Pragma("unroll") for (int rr = 0; rr < 2; ++rr)                             \
    gload_lds16(bBt + (size_t)(rr * 64) * 2048, LB(K2_) + rr * 4096 + wofs);   \
  aBt += 64; bBt += 64;

#define GA_MFMA_M(M_)                                                          \
  _Pragma("unroll") for (int kk = 0; kk < 2; ++kk)                             \
    _Pragma("unroll") for (int ni = 0; ni < 4; ++ni)                           \
      acc[M_][ni] = MFMA16(af[M_][kk].b, bfr[ni][kk].b, acc[M_][ni]);

// Read order (load-bearing for the counted waits): 8 B reads, then A pairs
// in m order. lgkmcnt(6)=B+af0 done; (4)=+af1; (2)=+af2; (0)=all.
#define GA_BODY(K_, K2_, VMSTR_, DOSTAGE_)                                     \
  {                                                                            \
    B128 af[4][2], bfr[4][2];                                                  \
    asm volatile("s_waitcnt vmcnt(" VMSTR_ ")" ::: "memory");                  \
    __builtin_amdgcn_s_barrier();                                              \
    DSR_OFS(b0[K_], "0",    bfr[0][0]); DSR_OFS(b0[K_], "2048", bfr[1][0]);    \
    DSR_OFS(b0[K_], "4096", bfr[2][0]); DSR_OFS(b0[K_], "6144", bfr[3][0]);    \
    DSR_OFS(b1[K_], "0",    bfr[0][1]); DSR_OFS(b1[K_], "2048", bfr[1][1]);    \
    DSR_OFS(b1[K_], "4096", bfr[2][1]); DSR_OFS(b1[K_], "6144", bfr[3][1]);    \
    DSR_OFS(a0[K_], "0",    af[0][0]);  DSR_OFS(a1[K_], "0",    af[0][1]);     \
    DSR_OFS(a0[K_], "2048", af[1][0]);  DSR_OFS(a1[K_], "2048", af[1][1]);     \
    DSR_OFS(a0[K_], "4096", af[2][0]);  DSR_OFS(a1[K_], "4096", af[2][1]);     \
    DSR_OFS(a0[K_], "6144", af[3][0]);  DSR_OFS(a1[K_], "6144", af[3][1]);     \
    if (DOSTAGE_) { GA_STAGE(K2_); }                                           \
    asm volatile("s_waitcnt lgkmcnt(6)" ::: "memory");                         \
    SBAR;                                                                      \
    __builtin_amdgcn_s_setprio(1);                                             \
    GA_MFMA_M(0);                                                              \
    asm volatile("s_waitcnt lgkmcnt(4)" ::: "memory");                         \
    SBAR;                                                                      \
    GA_MFMA_M(1);                                                              \
    asm volatile("s_waitcnt lgkmcnt(2)" ::: "memory");                         \
    SBAR;                                                                      \
    GA_MFMA_M(2);                                                              \
    asm volatile("s_waitcnt lgkmcnt(0)" ::: "memory");                         \
    SBAR;                                                                      \
    GA_MFMA_M(3);                                                              \
    __builtin_amdgcn_s_setprio(0);                                             \
  }

  f32x4 acc[4][4];
#pragma unroll
  for (int i = 0; i < 4; ++i)
#pragma unroll
    for (int j = 0; j < 4; ++j) acc[i][j] = (f32x4)(0.0f);

  // prologue: stage tiles 0 (slot 0) and 1 (slot 1); 12 issues/wave
  GA_STAGE(0);
  GA_STAGE(1);

  for (int t3 = 0; t3 < 30; t3 += 3) {
    GA_BODY(0, 2, "6", 1);   // t = t3:   slot 0, stage t3+2 -> slot 2
    GA_BODY(1, 0, "6", 1);   // t = t3+1: slot 1, stage t3+3 -> slot 0
    GA_BODY(2, 1, "6", 1);   // t = t3+2: slot 2, stage t3+4 -> slot 1
  }
  GA_BODY(0, 2, "6", 0);     // t = 30: slot 0, no stage
  GA_BODY(1, 0, "0", 0);     // t = 31: slot 1, drain

#pragma unroll
  for (int mi = 0; mi < 4; ++mi) {
#pragma unroll
    for (int rr = 0; rr < 4; ++rr) {
      int r = tm * 256 + wm * 64 + mi * 16 + g16 * 4 + rr;
      if (MODE == 0) {
        int rp = permrow(r);
#pragma unroll
        for (int ni = 0; ni < 4; ++ni) {
          int c = tn * 128 + wn * 64 + ni * 16 + cl;
          float v = acc[mi][ni][rr];
          if (c < 2048)      Cq[(size_t)rp * 2048 + c] = (bf16_t)(v * QSC);
          else if (c < 2560) Ck[(size_t)rp * 512 + (c - 2048)] = (bf16_t)v;
          else               Cv[(size_t)rp * 512 + (c - 2560)] = (bf16_t)v;
        }
      } else {
#pragma unroll
        for (int ni = 0; ni < 4; ++ni) {
          int c = tn * 128 + wn * 64 + ni * 16 + cl;
          Cf[(size_t)r * 2048 + c] = acc[mi][ni][rr];
        }
      }
    }
  }
}

// m214-style swapped-QK^T flash attention (round-13 body, unchanged).
__global__ __launch_bounds__(256, 2) void k_attn(
    const bf16_t* __restrict__ Qp, const bf16_t* __restrict__ Kp,
    const bf16_t* __restrict__ Vp, bf16_t* __restrict__ O) {
  int bid = blockIdx.x;
  int qc = bid & 7;
  int h  = (bid >> 3) & 31;
  int n  = bid >> 8;
  int kvh = h >> 2;

  __shared__ bf16_t buf[2][8192];

  int tid = threadIdx.x, lane = tid & 63, w = tid >> 6;
  int l31 = lane & 31, hi = lane >> 5;
  int qrow_blk = n * 1024 + qc * 128;
  bf16_t* base = &buf[0][0];

#pragma unroll
  for (int r = 0; r < 4; ++r) {
    int ql = r * 32 + (tid >> 3);
    int cs = (tid & 7) << 4;
    int lc = (cs ^ ((ql & 7) << 4)) >> 1;
    gload_lds16(Qp + (size_t)(qrow_blk + ql) * 2048 + h * 64 + lc,
                base + r * 2048 + w * 512);
  }
  __syncthreads();
  bf16x8 qf[4];
  {
    int q = w * 32 + l31;
    const bf16_t* qrow = base + q * 64;
    int sw = (q & 7) << 4;
#pragma unroll
    for (int c = 0; c < 4; ++c)
      qf[c] = *(const bf16x8*)(qrow + (((c * 32 + hi * 16) ^ sw) >> 1));
  }
  __syncthreads();

  f32x16 oacc0 = (f32x16)(0.0f), oacc1 = (f32x16)(0.0f);
  float m_run = -1e30f, l_run = 0.0f;

  auto stageKV = [&](int t) {
    bf16_t* bp = &buf[t & 1][0];
    int kvb = n * 1024 + t * 64;
#pragma unroll
    for (int r = 0; r < 2; ++r) {
      int kv = r * 32 + (tid >> 3);
      int cs = (tid & 7) << 4;
      int lc = (cs ^ ((kv & 7) << 4)) >> 1;
      gload_lds16(Kp + (size_t)(kvb + kv) * 512 + kvh * 64 + lc,
                  bp + r * 2048 + w * 512);
    }
#pragma unroll
    for (int r = 0; r < 2; ++r) {
      int slot = r * 256 + tid;
      int sub = slot >> 3;
      int kb = sub >> 2, db = sub & 3;
      int j = (slot >> 1) & 3, hf = slot & 1;
      gload_lds16(Vp + (size_t)(kvb + kb * 4 + j) * 512 + kvh * 64 + db * 16 + hf * 8,
                  bp + 4096 + r * 2048 + w * 512);
    }
  };

  stageKV(0);
  for (int t = 0; t < 16; ++t) {
    __syncthreads();
    if (t < 15) stageKV(t + 1);
    const bf16_t* bp = &buf[t & 1][0];
    const bf16_t* Vs = bp + 4096;

#pragma unroll
    for (int s = 0; s < 2; ++s) {
      f32x16 st = (f32x16)(0.0f);
      {
        int kv = s * 32 + l31;
        const bf16_t* krow = bp + kv * 64;
        int sw = (kv & 7) << 4;
#pragma unroll
        for (int c = 0; c < 4; ++c) {
          bf16x8 kf = *(const bf16x8*)(krow + (((c * 32 + hi * 16) ^ sw) >> 1));
          st = MFMA32(kf, qf[c], st);
        }
      }
      // pmax via v_max3-friendly nesting
      float p0 = fmaxf(fmaxf(st[0], st[1]), st[2]);
      float p1 = fmaxf(fmaxf(st[3], st[4]), st[5]);
      float p2 = fmaxf(fmaxf(st[6], st[7]), st[8]);
      float p3 = fmaxf(fmaxf(st[9], st[10]), st[11]);
      float p4 = fmaxf(fmaxf(st[12], st[13]), st[14]);
      float pmax = fmaxf(fmaxf(fmaxf(p0, p1), p2),
                         fmaxf(fmaxf(p3, p4), st[15]));
      pmax = fmaxf(pmax, __shfl_xor(pmax, 32));
      if (!__all(pmax <= m_run + 11.0f)) {
        float mnew = fmaxf(m_run, pmax);
        float resc = EXP2F(m_run - mnew);
        l_run *= resc;
#pragma unroll
        for (int e = 0; e < 16; ++e) { oacc0[e] *= resc; oacc1[e] *= resc; }
        m_run = mnew;
      }
      float rs = 0.0f;
      unsigned pw[8];
#pragma unroll
      for (int u = 0; u < 8; ++u) {
        float q0 = EXP2F(st[2 * u] - m_run);
        float q1 = EXP2F(st[2 * u + 1] - m_run);
        rs += q0 + q1;
        pw[u] = cvt_pk_bf16(q0, q1);
      }
      rs += __shfl_xor(rs, 32);
      l_run += rs;

#pragma unroll
      for (int c = 0; c < 2; ++c) {
        unsigned w2, w0, w3, w1;
        swap32(pw[c * 4 + 2], pw[c * 4 + 0], hi, w2, w0);
        swap32(pw[c * 4 + 3], pw[c * 4 + 1], hi, w3, w1);
        union { unsigned u[4]; bf16x8 v; } pa;
        pa.u[0] = w0; pa.u[1] = w1; pa.u[2] = w2; pa.u[3] = w3;
        int kb0 = s * 8 + c * 4 + hi * 2;
        int dbl = l31 >> 4;
        int cc8 = (l31 & 15) * 4;
        const bf16_t* p00 = Vs + (kb0 * 4 + dbl) * 64 + cc8;
        const bf16_t* p01 = Vs + ((kb0 + 1) * 4 + dbl) * 64 + cc8;
        const bf16_t* p10 = Vs + (kb0 * 4 + 2 + dbl) * 64 + cc8;
        const bf16_t* p11 = Vs + ((kb0 + 1) * 4 + 2 + dbl) * 64 + cc8;
        s16x4 t00 = tr_b16(p00), t01 = tr_b16(p01);
        s16x4 t10 = tr_b16(p10), t11 = tr_b16(p11);
        asm volatile("s_waitcnt lgkmcnt(0)" ::: "memory");
        __builtin_amdgcn_sched_barrier(0);
        union { s16x4 s4[2]; bf16x8 v; } vf0, vf1;
        vf0.s4[0] = t00; vf0.s4[1] = t01;
        vf1.s4[0] = t10; vf1.s4[1] = t11;
        oacc0 = MFMA32(pa.v, vf0.v, oacc0);
        oacc1 = MFMA32(pa.v, vf1.v, oacc1);
      }
    }
  }

  float linv = 1.0f / l_run;
#pragma unroll
  for (int r = 0; r < 16; ++r) {
    int qrw = (r & 3) + 8 * (r >> 2) + 4 * hi;
    float li = __shfl(linv, qrw);
    size_t orow = (size_t)(qrow_blk + w * 32 + qrw) * 2048 + h * 64 + l31;
    O[orow]      = (bf16_t)(oacc0[r] * li);
    O[orow + 32] = (bf16_t)(oacc1[r] * li);
  }
}

extern "C" void kernel_launch(void* const* d_in, const int* in_sizes, int n_in,
                              void* d_out, int out_size, void* d_ws, size_t ws_size,
                              hipStream_t stream) {
  const float* X  = (const float*)d_in[0];
  const float* Wq = (const float*)d_in[1];
  const float* Wk = (const float*)d_in[2];
  const float* Wv = (const float*)d_in[3];
  const float* Wo = (const float*)d_in[4];
  float* out = (float*)d_out;

  char* ws = (char*)d_ws;
  const size_t MB = 1024 * 1024;
  bf16_t* Xb  = (bf16_t*)(ws + 0);
  bf16_t* WqT = (bf16_t*)(ws + 32 * MB);
  bf16_t* WkT = (bf16_t*)(ws + 40 * MB);
  bf16_t* WvT = (bf16_t*)(ws + 42 * MB);
  bf16_t* WoT = (bf16_t*)(ws + 44 * MB);
  bf16_t* Qp  = (bf16_t*)(ws + 52 * MB);
  bf16_t* Kp  = (bf16_t*)(ws + 84 * MB);
  bf16_t* Vp  = (bf16_t*)(ws + 92 * MB);
  bf16_t* Ob  = (bf16_t*)(ws + 100 * MB);

  hipFuncSetAttribute(reinterpret_cast<const void*>(&k_gemm15<0>),
                      hipFuncAttributeMaxDynamicSharedMemorySize, 147456);
  hipFuncSetAttribute(reinterpret_cast<const void*>(&k_gemm15<1>),
                      hipFuncAttributeMaxDynamicSharedMemorySize, 147456);

  k_convert<<<16384, 256, 0, stream>>>(X, Xb, 4194304);
  k_transpose<<<dim3(32, 32), 256, 0, stream>>>(Wq, WqT, 2048, 2048);
  k_transpose<<<dim3(8, 32), 256, 0, stream>>>(Wk, WkT, 2048, 512);
  k_transpose<<<dim3(8, 32), 256, 0, stream>>>(Wv, WvT, 2048, 512);
  k_transpose<<<dim3(32, 32), 256, 0, stream>>>(Wo, WoT, 2048, 2048);

  k_gemm15<0><<<768, 512, 147456, stream>>>(Xb, WqT, WkT, WvT, Qp, Kp, Vp,
                                            nullptr);
  k_attn<<<2048, 256, 0, stream>>>(Qp, Kp, Vp, Ob);
  k_gemm15<1><<<512, 512, 147456, stream>>>(Ob, WoT, nullptr, nullptr, nullptr,
                                            nullptr, nullptr, out);
}